// Round 4
// baseline (146.798 us; speedup 1.0000x reference)
//
#include <hip/hip_runtime.h>
#include <math.h>

#define A_ 5
#define C_ 20
#define N_ 64
#define H_ 52
#define W_ 52
#define HW_ (H_ * W_)        // 2704
#define M_ 32
#define CH_ (A_ * (5 + C_))  // 125
#define CPB 128              // cells per block
#define NBX ((HW_ + CPB - 1) / CPB)  // 22
#define NBLK (NBX * N_)              // 1408

// Block = 320 threads = 5 waves; wave a = anchor a; lane handles 2 cells
// (float2 loads). Tail: threads 0..127 handle 1 cell each (2 waves wide).
__global__ __launch_bounds__(320) void yolo_main(
    const float* __restrict__ x,       // (N, 125, H, W)
    const float* __restrict__ anchors, // (5, 2)
    const float* __restrict__ gt,      // (N, 32, 4)
    const int* __restrict__ glab,      // (N, 32)
    const void* img_h_p, const void* img_w_p,
    float* __restrict__ ws)            // (NBLK, 3)
{
    // SoA planes: 0=bi 1=bu 2=bm 3=ov 4=x1 5=y1 6=x2 7=y2  (20 KB)
    __shared__ float s_c[8][A_][CPB];
    __shared__ float s_red[5][3];

    const int tid  = threadIdx.x;
    const int a    = tid >> 6;
    const int lane = tid & 63;
    const int n    = blockIdx.y;
    const int c0   = blockIdx.x * CPB + 2 * lane;  // even; HW_ even -> pair all-or-none valid
    const bool v2  = c0 < HW_;

    int ibw = *(const int*)img_w_p;
    float img_w = (ibw > 0 && ibw < 1000000) ? (float)ibw : *(const float*)img_w_p;
    int ibh = *(const int*)img_h_p;
    float img_h = (ibh > 0 && ibh < 1000000) ? (float)ibh : *(const float*)img_h_p;
    const float sx = img_w / (float)W_;
    const float sy = img_h / (float)H_;

    const float ax = anchors[2 * a];
    const float ay = anchors[2 * a + 1];

    float X1[2] = {0.f, 0.f}, Y1[2] = {0.f, 0.f}, X2[2] = {0.f, 0.f}, Y2[2] = {0.f, 0.f};
    float AP[2] = {0.f, 0.f}, OV[2] = {0.f, 0.f};
    float bi[2] = {0.f, 0.f}, bu[2] = {1.f, 1.f};
    int   bm[2] = {0, 0};

    if (v2) {
        const size_t base = (size_t)n * CH_ * HW_ + (size_t)a * 25 * HW_ + c0;
        const float2* p = (const float2*)(x + base);   // 8B-aligned: c0 even, HW_ even
        float2 t0 = p[0];
        float2 t1 = p[HW_ / 2];
        float2 t2 = p[HW_];
        float2 t3 = p[3 * HW_ / 2];
        float2 t4 = p[2 * HW_];
        #pragma unroll
        for (int s = 0; s < 2; ++s) {
            const int cell = c0 + s;
            const int wi = cell % W_;
            const int hi = cell / W_;
            float u0 = s ? t0.y : t0.x;
            float u1 = s ? t1.y : t1.x;
            float u2 = s ? t2.y : t2.x;
            float u3 = s ? t3.y : t3.x;
            float u4 = s ? t4.y : t4.x;
            float bx = 1.f / (1.f + __expf(-u0)) + (float)wi * sx;
            float by = 1.f / (1.f + __expf(-u1)) + (float)hi * sy;
            float bw = sx * ax * __expf(u2);
            float bh = sy * ay * __expf(u3);
            X1[s] = bx; Y1[s] = by; X2[s] = bx + bw; Y2[s] = by + bh;
            AP[s] = (X2[s] - X1[s]) * (Y2[s] - Y1[s]);
            OV[s] = 1.f / (1.f + __expf(-u4));
        }
    }

    // IoU argmax over 32 GT boxes, 2 independent chains (cross-mult, first-max)
    const float4* gtv = (const float4*)(gt + (size_t)n * M_ * 4);
    #pragma unroll 4
    for (int m = 0; m < M_; ++m) {
        float4 g = gtv[m];                    // uniform -> scalar load
        float area = (g.z - g.x) * (g.w - g.y);
        #pragma unroll
        for (int s = 0; s < 2; ++s) {
            float wxi = fminf(X2[s], g.z) - fmaxf(X1[s], g.x);
            float hyi = fminf(Y2[s], g.w) - fmaxf(Y1[s], g.y);
            wxi = fmaxf(wxi, 0.f);
            hyi = fmaxf(hyi, 0.f);
            float inter = wxi * hyi;
            float uni = AP[s] + area - inter;
            if (inter * bu[s] > bi[s] * uni) { bi[s] = inter; bu[s] = uni; bm[s] = m; }
        }
    }

    // SoA exchange, float2 stores (stride-1 in cell -> conflict-free)
    {
        float2* pl;
        pl = (float2*)&s_c[0][a][0]; pl[lane] = make_float2(bi[0], bi[1]);
        pl = (float2*)&s_c[1][a][0]; pl[lane] = make_float2(bu[0], bu[1]);
        pl = (float2*)&s_c[2][a][0]; pl[lane] = make_float2(__int_as_float(bm[0]), __int_as_float(bm[1]));
        pl = (float2*)&s_c[3][a][0]; pl[lane] = make_float2(OV[0], OV[1]);
        pl = (float2*)&s_c[4][a][0]; pl[lane] = make_float2(X1[0], X1[1]);
        pl = (float2*)&s_c[5][a][0]; pl[lane] = make_float2(Y1[0], Y1[1]);
        pl = (float2*)&s_c[6][a][0]; pl[lane] = make_float2(X2[0], X2[1]);
        pl = (float2*)&s_c[7][a][0]; pl[lane] = make_float2(Y2[0], Y2[1]);
    }
    __syncthreads();

    // ---- tail: one thread per cell (threads 0..127 = 2 waves) ----
    float obj = 0.f, bbx = 0.f, clf = 0.f;
    const int tcell = blockIdx.x * CPB + tid;
    if (tid < CPB && tcell < HW_) {
        float Bi = 0.f, Bu = 1.f, O = 0.f;
        float BX1 = 0.f, BY1 = 0.f, BX2 = 0.f, BY2 = 0.f;
        int Ba = 0, Bm = 0;
        float bomax = -1e30f;
        #pragma unroll
        for (int aa = 0; aa < A_; ++aa) {
            float ci = s_c[0][aa][tid];
            float cu = s_c[1][aa][tid];
            float co = s_c[3][aa][tid];
            bomax = fmaxf(bomax, co);
            bool upd = (aa == 0) || (ci * Bu > Bi * cu);
            if (upd) {
                Bi = ci; Bu = cu; Ba = aa; O = co;
                Bm = __float_as_int(s_c[2][aa][tid]);
                BX1 = s_c[4][aa][tid]; BY1 = s_c[5][aa][tid];
                BX2 = s_c[6][aa][tid]; BY2 = s_c[7][aa][tid];
            }
        }

        if (Bi > 0.f) {
            float miou = Bi / Bu;
            float d = O - miou;
            obj = d * d;

            float4 g = ((const float4*)gt)[n * M_ + Bm];
            float d0 = BX1 - g.x;
            float d1 = BY1 - g.y;
            float d2 = sqrtf(BX2) - sqrtf(g.z);
            float d3 = sqrtf(BY2) - sqrtf(g.w);
            bbx = d0 * d0 + d1 * d1 + d2 * d2 + d3 * d3;

            // CE via online softmax over best anchor's 20 scores
            const size_t sb = (size_t)n * CH_ * HW_ + (size_t)(Ba * 25 + 5) * HW_ + tcell;
            const int lab = glab[n * M_ + Bm];
            float mx = -1e30f, se = 0.f, scl = 0.f;
            #pragma unroll
            for (int j = 0; j < C_; ++j) {
                float v = x[sb + (size_t)j * HW_];
                float nm = fmaxf(mx, v);
                se = se * __expf(mx - nm) + __expf(v - nm);
                mx = nm;
                scl = (j == lab) ? v : scl;
            }
            clf = mx + __logf(se) - scl;
        } else {
            obj = 0.5f * bomax * bomax;
        }
    }

    // all 320 threads reduce (waves 2-4 contribute zeros)
    #pragma unroll
    for (int off = 32; off > 0; off >>= 1) {
        obj += __shfl_down(obj, off, 64);
        bbx += __shfl_down(bbx, off, 64);
        clf += __shfl_down(clf, off, 64);
    }
    if (lane == 0) {
        s_red[a][0] = obj; s_red[a][1] = bbx; s_red[a][2] = clf;
    }
    __syncthreads();
    if (tid == 0) {
        float oo = 0.f, bb = 0.f, cc = 0.f;
        #pragma unroll
        for (int w = 0; w < 5; ++w) {
            oo += s_red[w][0]; bb += s_red[w][1]; cc += s_red[w][2];
        }
        const int bid = blockIdx.y * gridDim.x + blockIdx.x;
        ws[bid * 3 + 0] = oo;
        ws[bid * 3 + 1] = bb;
        ws[bid * 3 + 2] = cc;
    }
}

__global__ __launch_bounds__(256) void yolo_reduce(
    const float* __restrict__ ws, float* __restrict__ out)
{
    __shared__ float s_red[4][3];
    const int tid = threadIdx.x;
    float o = 0.f, b = 0.f, c = 0.f;
    for (int e = tid; e < NBLK; e += 256) {
        o += ws[e * 3 + 0];
        b += ws[e * 3 + 1];
        c += ws[e * 3 + 2];
    }
    #pragma unroll
    for (int off = 32; off > 0; off >>= 1) {
        o += __shfl_down(o, off, 64);
        b += __shfl_down(b, off, 64);
        c += __shfl_down(c, off, 64);
    }
    const int wid = tid >> 6;
    if ((tid & 63) == 0) {
        s_red[wid][0] = o; s_red[wid][1] = b; s_red[wid][2] = c;
    }
    __syncthreads();
    if (tid == 0) {
        float oo = 0.f, bb = 0.f, cc = 0.f;
        #pragma unroll
        for (int w = 0; w < 4; ++w) {
            oo += s_red[w][0]; bb += s_red[w][1]; cc += s_red[w][2];
        }
        out[0] = oo; out[1] = bb; out[2] = cc;
    }
}

extern "C" void kernel_launch(void* const* d_in, const int* in_sizes, int n_in,
                              void* d_out, int out_size, void* d_ws, size_t ws_size,
                              hipStream_t stream) {
    const float* x    = (const float*)d_in[0];
    const float* anch = (const float*)d_in[1];
    const float* gt   = (const float*)d_in[2];
    const int*   gl   = (const int*)d_in[3];
    const void*  ih   = d_in[4];
    const void*  iw   = d_in[5];
    float* out = (float*)d_out;
    float* ws  = (float*)d_ws;

    dim3 grid(NBX, N_);
    yolo_main<<<grid, dim3(320), 0, stream>>>(x, anch, gt, gl, ih, iw, ws);
    yolo_reduce<<<1, 256, 0, stream>>>(ws, out);
}